// Round 4
// baseline (698.160 us; speedup 1.0000x reference)
//
#include <hip/hip_runtime.h>
#include <hip/hip_bf16.h>
#include <stdint.h>

#define B_   2048
#define P_   20
#define D_   64
#define V_   100000
#define T_   33
#define FIN  2240          // 35*64
#define KE   2112          // 33*64  (emb-only K; raw cols folded into epilogue)
#define M_   (B_*P_)       // 40960
#define H1_  512
#define H2_  256
#define NKT  33            // K-tiles of 64

using bf16 = __hip_bfloat16;
typedef __bf16 bf16x8 __attribute__((ext_vector_type(8)));
typedef float  f32x4  __attribute__((ext_vector_type(4)));

__device__ __forceinline__ unsigned short f2b(float f) {
    bf16 h = __float2bfloat16(f);
    return __builtin_bit_cast(unsigned short, h);
}

__device__ __forceinline__ void gload16(const void* g, void* l) {
    __builtin_amdgcn_global_load_lds(
        (const __attribute__((address_space(1))) uint32_t*)g,
        (__attribute__((address_space(3))) uint32_t*)l, 16, 0, 0);
}

// ---------------------------------------------------------------------------
// prep 1: column sums of W1 rows 0..63 (S0) and 64..127 (S1).  S01 = [S0|S1]
// ---------------------------------------------------------------------------
__global__ __launch_bounds__(256) void colsum_k(
    const float* __restrict__ W1, float* __restrict__ S01)
{
    int g = blockIdx.x * 256 + threadIdx.x;   // 0..1023
    int s = g >> 9, n = g & 511;
    const float* p = W1 + (size_t)(s * 64) * H1_ + n;
    float acc = 0.f;
    #pragma unroll 8
    for (int k = 0; k < 64; ++k) acc += p[(size_t)k * H1_];
    S01[s * H1_ + n] = acc;
}

// ---------------------------------------------------------------------------
// prep 2: W1 rows 128.. -> W1t (512 x 2112) bf16 row-major (transposed)
// ---------------------------------------------------------------------------
__global__ __launch_bounds__(256) void w1t_k(
    const float* __restrict__ W1, bf16* __restrict__ W1t)
{
    int idx = blockIdx.x * 256 + threadIdx.x;   // n*KE + k
    int n = idx / KE;
    int k = idx - n * KE;
    W1t[idx] = __float2bfloat16(W1[(size_t)(k + 128) * H1_ + n]);
}

// ---------------------------------------------------------------------------
// prep 3: generic W (K x N fp32) -> Wt (N x K bf16)
// ---------------------------------------------------------------------------
__global__ __launch_bounds__(256) void transpose_bf16_k(
    const float* __restrict__ W, bf16* __restrict__ Wt, int K, int N)
{
    int idx = blockIdx.x * 256 + threadIdx.x;
    if (idx >= N * K) return;
    int n = idx / K;
    int k = idx - n * K;
    Wt[idx] = __float2bfloat16(W[(size_t)k * N + n]);
}

// ---------------------------------------------------------------------------
// FUSED gather + GEMM1:  h1 = relu(feat @ W1 + b1)
//   R2's proven layout (reg-staged bf16 A, single 20KB A-LDS, dbuf 2x64KB B,
//   verified swizzles) + T4 pipelining: raw s_barrier (no vmcnt drain), and
//   issue-order arranged so every compiler auto-wait only drains loads that
//   are one full iteration old.  18 loads/wave stay in flight across both
//   barriers every iteration.
// ---------------------------------------------------------------------------
__global__ __launch_bounds__(512, 2) void fused_gemm1_k(
    const float* __restrict__ x_raw, const int* __restrict__ x_idx,
    const float* __restrict__ emb, const bf16* __restrict__ W1t,
    const float* __restrict__ b1, const float* __restrict__ S01,
    bf16* __restrict__ h1)
{
    extern __shared__ char smem[];
    char* Als = smem;            // [160][64] bf16, swizzled, 20480 B
    char* Bls = smem + 20480;    // 2 x [512][64] bf16, swizzled, 2 x 65536 B

    const int tid = threadIdx.x;
    const int w  = tid >> 6, l = tid & 63;
    const int wr = w >> 2, wc = w & 3;         // 2 x 4 wave grid
    const int fr = l & 15, fq = l >> 4;
    const int m0 = blockIdx.x * 160;

    // A staging role: row r = p*32 + arow, 16 lanes per row (cols ali*4..+3)
    const int arow = tid >> 4;                 // 0..31
    const int ali  = tid & 15;

    // B staging role (per wave, q=0..7): dest o = q*8192 + w*1024 + 16*l
    //   row n = q*64 + w*8 + (l>>3); pre-swizzled source col byte
    const int bn   = w * 8 + (l >> 3);
    const int bcolb = 16 * ((l & 7) ^ (l >> 3));

    f32x4  acc[5][8] = {};
    float4 areg[5];
    int    iv0[5], iv1[5];

    auto load_idx = [&](int t, int (&iv)[5]) {
        #pragma unroll
        for (int p = 0; p < 5; ++p)
            iv[p] = x_idx[(size_t)(m0 + p * 32 + arow) * T_ + t];
    };
    auto issue_A = [&](int t, const int (&iv)[5]) {
        #pragma unroll
        for (int p = 0; p < 5; ++p)
            areg[p] = *reinterpret_cast<const float4*>(
                emb + ((size_t)t * V_ + (size_t)iv[p]) * D_ + ali * 4);
    };
    auto issue_B = [&](int kt, int buf) {
        char* base = Bls + buf * 65536 + w * 1024;
        #pragma unroll
        for (int q = 0; q < 8; ++q)
            gload16((const char*)(W1t + (size_t)(q * 64 + bn) * KE + kt * 64) + bcolb,
                    base + q * 8192);
    };
    auto write_A = [&]() {
        #pragma unroll
        for (int p = 0; p < 5; ++p) {
            int r = p * 32 + arow;
            ushort4 o;
            o.x = f2b(areg[p].x); o.y = f2b(areg[p].y);
            o.z = f2b(areg[p].z); o.w = f2b(areg[p].w);
            int byte = (r * 128 + ali * 8) ^ ((r & 7) << 4);
            *reinterpret_cast<ushort4*>(Als + byte) = o;
        }
    };

    auto body = [&](int kt, int (&ivUse)[5], int (&ivLoad)[5]) {
        // 1) A(kt) regs -> LDS (auto-waits the A(kt) gather: 1 iter old)
        write_A();
        // 2) next-tile issues.  issue_A's idx auto-wait drains B(kt) too
        //    (both 1 iter old == cheap) -- that IS the B(kt) guarantee.
        if (kt + 1 < NKT) {
            issue_A(kt + 1, ivUse);
            issue_B(kt + 1, (kt + 1) & 1);
        }
        if (kt + 2 < NKT) load_idx(kt + 2, ivLoad);
        // 3) LDS writes visible, then barrier.  Fresh loads stay in flight.
        asm volatile("s_waitcnt lgkmcnt(0)" ::: "memory");
        __builtin_amdgcn_s_barrier();
        __builtin_amdgcn_sched_barrier(0);

        // 4) MFMA(kt)
        const char* Bbase = Bls + (kt & 1) * 65536;
        __builtin_amdgcn_s_setprio(1);
        #pragma unroll
        for (int kk = 0; kk < 2; ++kk) {
            bf16x8 af[5];
            #pragma unroll
            for (int i = 0; i < 5; ++i) {
                int r = wr * 80 + i * 16 + fr;
                int byte = (r * 128 + kk * 64 + fq * 16) ^ ((r & 7) << 4);
                af[i] = *reinterpret_cast<const bf16x8*>(Als + byte);
            }
            #pragma unroll
            for (int j = 0; j < 8; ++j) {
                int n    = wc * 128 + j * 16 + fr;
                int byte = (n * 128 + kk * 64 + fq * 16) ^ ((n & 7) << 4);
                bf16x8 bg = *reinterpret_cast<const bf16x8*>(Bbase + byte);
                #pragma unroll
                for (int i = 0; i < 5; ++i)
                    acc[i][j] = __builtin_amdgcn_mfma_f32_16x16x32_bf16(
                        af[i], bg, acc[i][j], 0, 0, 0);
            }
        }
        __builtin_amdgcn_s_setprio(0);
        // 5) reads retired, then barrier (no vmcnt drain)
        asm volatile("s_waitcnt lgkmcnt(0)" ::: "memory");
        __builtin_amdgcn_s_barrier();
    };

    // prologue: A(0) gather, B(0) -> buf0, idx(1).  In-flight: 5+8+5.
    load_idx(0, iv0);
    issue_A(0, iv0);       // auto-waits idx(0)
    issue_B(0, 0);
    load_idx(1, iv1);

    // steady: even kt consumes iv1, reloads iv0; odd the reverse.
    for (int kt = 0; kt < NKT - 1; kt += 2) {
        body(kt,     iv1, iv0);
        body(kt + 1, iv0, iv1);
    }
    body(NKT - 1, iv1, iv0);   // kt=32: no new issues

    // epilogue: bias + rank-2 raw contribution + relu -> h1 (bf16)
    const float* S0 = S01;
    const float* S1 = S01 + H1_;
    #pragma unroll
    for (int i = 0; i < 5; ++i) {
        int rbase = wr * 80 + i * 16 + fq * 4;
        float x0[4], x1[4];
        #pragma unroll
        for (int r2 = 0; r2 < 4; ++r2) {
            int m = m0 + rbase + r2;
            x0[r2] = x_raw[2 * m];
            x1[r2] = x_raw[2 * m + 1];
        }
        #pragma unroll
        for (int j = 0; j < 8; ++j) {
            int n = wc * 128 + j * 16 + fr;
            float bb = b1[n], s0 = S0[n], s1 = S1[n];
            #pragma unroll
            for (int r2 = 0; r2 < 4; ++r2) {
                float v = acc[i][j][r2] + bb + x0[r2] * s0 + x1[r2] * s1;
                h1[(size_t)(m0 + rbase + r2) * H1_ + n] =
                    __float2bfloat16(fmaxf(v, 0.0f));
            }
        }
    }
}

// ---------------------------------------------------------------------------
// FUSED GEMM2 + head:  h2 = relu(h1 @ W2 + b2); logits = h2 @ W3 + b3;
// softmax over P=20.  BM=160 (=8 batches), BN=256 (full).  grid 256,
// 8 waves (2x4), wave tile 80x64.  (passed in R3, unchanged)
// ---------------------------------------------------------------------------
__global__ __launch_bounds__(512) void gemm2_head_k(
    const bf16* __restrict__ h1, const bf16* __restrict__ W2t,
    const float* __restrict__ b2, const float* __restrict__ W3,
    const float* __restrict__ b3, float* __restrict__ out)
{
    __shared__ char  As[20480];       // [160][64] bf16 swizzled
    __shared__ char  Bs[32768];       // [256][64] bf16 swizzled
    __shared__ float w3s[H2_];
    __shared__ float b2s[H2_];
    __shared__ float logq[4][160];
    __shared__ float logits[160];

    const int tid = threadIdx.x;
    const int w = tid >> 6, l = tid & 63;
    const int wr = w >> 2, wc = w & 3;
    const int fr = l & 15, fq = l >> 4;
    const int m0 = blockIdx.x * 160;
    const int r8 = l >> 3, c8 = l & 7;

    if (tid < H2_) { w3s[tid] = W3[tid]; b2s[tid] = b2[tid]; }

    f32x4 acc[5][4] = {};

    for (int kt = 0; kt < 8; ++kt) {
        for (int s = w; s < 20; s += 8) {
            int row = s * 8 + r8;
            const char* src = (const char*)(h1 + (size_t)(m0 + row) * H1_ + kt * 64)
                              + ((16 * c8) ^ ((row & 7) << 4));
            gload16(src, As + s * 1024);
        }
        #pragma unroll
        for (int q = 0; q < 4; ++q) {
            int s = q * 8 + w;
            int row = s * 8 + r8;
            const char* src = (const char*)(W2t + (size_t)row * H1_ + kt * 64)
                              + ((16 * c8) ^ ((row & 7) << 4));
            gload16(src, Bs + s * 1024);
        }
        __syncthreads();

        #pragma unroll
        for (int kk = 0; kk < 2; ++kk) {
            bf16x8 af[5];
            #pragma unroll
            for (int i = 0; i < 5; ++i) {
                int r = wr * 80 + i * 16 + fr;
                int byte = (r * 128 + kk * 64 + fq * 16) ^ ((r & 7) << 4);
                af[i] = *(const bf16x8*)(As + byte);
            }
            #pragma unroll
            for (int j = 0; j < 4; ++j) {
                int n = wc * 64 + j * 16 + fr;
                int byte = (n * 128 + kk * 64 + fq * 16) ^ ((n & 7) << 4);
                bf16x8 bg = *(const bf16x8*)(Bs + byte);
                #pragma unroll
                for (int i = 0; i < 5; ++i)
                    acc[i][j] = __builtin_amdgcn_mfma_f32_16x16x32_bf16(
                        af[i], bg, acc[i][j], 0, 0, 0);
            }
        }
        __syncthreads();
    }

    #pragma unroll
    for (int i = 0; i < 5; ++i) {
        #pragma unroll
        for (int r2 = 0; r2 < 4; ++r2) {
            float s = 0.f;
            #pragma unroll
            for (int j = 0; j < 4; ++j) {
                int col = wc * 64 + j * 16 + fr;
                float v = fmaxf(acc[i][j][r2] + b2s[col], 0.f);
                s += v * w3s[col];
            }
            #pragma unroll
            for (int off = 1; off < 16; off <<= 1) s += __shfl_xor(s, off);
            if (fr == 0)
                logq[wc][wr * 80 + i * 16 + fq * 4 + r2] = s;
        }
    }
    __syncthreads();
    if (tid < 160)
        logits[tid] = logq[0][tid] + logq[1][tid] + logq[2][tid] + logq[3][tid] + b3[0];
    __syncthreads();
    if (tid < 160) {
        int bb = (tid / 20) * 20;
        float mx = -1e30f;
        #pragma unroll
        for (int p = 0; p < 20; ++p) mx = fmaxf(mx, logits[bb + p]);
        float sum = 0.f;
        #pragma unroll
        for (int p = 0; p < 20; ++p) sum += expf(logits[bb + p] - mx);
        out[m0 + tid] = expf(logits[tid] - mx) / sum;
    }
}

// ---------------------------------------------------------------------------
extern "C" void kernel_launch(void* const* d_in, const int* in_sizes, int n_in,
                              void* d_out, int out_size, void* d_ws, size_t ws_size,
                              hipStream_t stream)
{
    const float* x_raw = (const float*)d_in[0];
    const int*   x_idx = (const int*)  d_in[1];
    const float* emb   = (const float*)d_in[2];
    const float* W1    = (const float*)d_in[3];
    const float* b1    = (const float*)d_in[4];
    const float* W2    = (const float*)d_in[5];
    const float* b2    = (const float*)d_in[6];
    const float* W3    = (const float*)d_in[7];
    const float* b3    = (const float*)d_in[8];

    char* ws = (char*)d_ws;
    size_t off = 0;
    bf16*  W1t = (bf16*) (ws + off); off += (size_t)H1_ * KE * 2;    // 2.16 MB
    bf16*  W2t = (bf16*) (ws + off); off += (size_t)H2_ * H1_ * 2;   // 0.26 MB
    float* S01 = (float*)(ws + off); off += (size_t)2 * H1_ * 4;     // 4 KB
    bf16*  h1  = (bf16*) (ws + off); off += (size_t)M_ * H1_ * 2;    // 42 MB

    // prep
    colsum_k<<<4, 256, 0, stream>>>(W1, S01);
    w1t_k<<<(H1_ * KE) / 256, 256, 0, stream>>>(W1, W1t);
    transpose_bf16_k<<<(H2_ * H1_ + 255) / 256, 256, 0, stream>>>(W2, W2t, H1_, H2_);

    // fused gather + GEMM1 (148 KB dynamic LDS)
    hipFuncSetAttribute((const void*)fused_gemm1_k,
                        hipFuncAttributeMaxDynamicSharedMemorySize, 151552);
    fused_gemm1_k<<<256, 512, 151552, stream>>>(x_raw, x_idx, emb, W1t, b1, S01, h1);

    // fused GEMM2 + head -> softmax out
    gemm2_head_k<<<256, 512, 0, stream>>>(h1, W2t, b2, W3, b3, (float*)d_out);
}

// Round 5
// 187.224 us; speedup vs baseline: 3.7290x; 3.7290x over previous
//
#include <hip/hip_runtime.h>
#include <hip/hip_bf16.h>
#include <stdint.h>

#define B_   2048
#define P_   20
#define D_   64
#define V_   100000
#define T_   33
#define FIN  2240          // 35*64
#define KE   2112          // 33*64  (emb-only K; raw cols folded into epilogue)
#define M_   (B_*P_)       // 40960
#define H1_  512
#define H2_  256
#define NKT  33            // K-tiles of 64

using bf16 = __hip_bfloat16;
typedef __bf16 bf16x8 __attribute__((ext_vector_type(8)));
typedef float  f32x4  __attribute__((ext_vector_type(4)));

__device__ __forceinline__ void gload16(const void* g, void* l) {
    __builtin_amdgcn_global_load_lds(
        (const __attribute__((address_space(1))) uint32_t*)g,
        (__attribute__((address_space(3))) uint32_t*)l, 16, 0, 0);
}
__device__ __forceinline__ void gload4(const void* g, void* l) {
    __builtin_amdgcn_global_load_lds(
        (const __attribute__((address_space(1))) uint32_t*)g,
        (__attribute__((address_space(3))) uint32_t*)l, 4, 0, 0);
}

// ---------------------------------------------------------------------------
// prep 1: column sums of W1 rows 0..63 (S0) and 64..127 (S1).  S01 = [S0|S1]
// ---------------------------------------------------------------------------
__global__ __launch_bounds__(256) void colsum_k(
    const float* __restrict__ W1, float* __restrict__ S01)
{
    int g = blockIdx.x * 256 + threadIdx.x;   // 0..1023
    int s = g >> 9, n = g & 511;
    const float* p = W1 + (size_t)(s * 64) * H1_ + n;
    float acc = 0.f;
    #pragma unroll 8
    for (int k = 0; k < 64; ++k) acc += p[(size_t)k * H1_];
    S01[s * H1_ + n] = acc;
}

// ---------------------------------------------------------------------------
// prep 2: W1 rows 128.. -> W1t (512 x 2112) bf16 row-major (transposed)
// ---------------------------------------------------------------------------
__global__ __launch_bounds__(256) void w1t_k(
    const float* __restrict__ W1, bf16* __restrict__ W1t)
{
    int idx = blockIdx.x * 256 + threadIdx.x;   // n*KE + k
    int n = idx / KE;
    int k = idx - n * KE;
    W1t[idx] = __float2bfloat16(W1[(size_t)(k + 128) * H1_ + n]);
}

// ---------------------------------------------------------------------------
// prep 3: generic W (K x N fp32) -> Wt (N x K bf16)
// ---------------------------------------------------------------------------
__global__ __launch_bounds__(256) void transpose_bf16_k(
    const float* __restrict__ W, bf16* __restrict__ Wt, int K, int N)
{
    int idx = blockIdx.x * 256 + threadIdx.x;
    if (idx >= N * K) return;
    int n = idx / K;
    int k = idx - n * K;
    Wt[idx] = __float2bfloat16(W[(size_t)k * N + n]);
}

// ---------------------------------------------------------------------------
// FUSED gather + GEMM1 (v5, all-global_load_lds pipeline):
//   h1 = relu(feat @ W1 + b1).  grid 256 (BM=160), 512 thr = 8 waves (2x4).
//   ALL main-loop global traffic is global_load_lds (no VGPR dests) so the
//   compiler emits no vmcnt waits; manual counted vmcnt is authoritative
//   (m201 pattern).  Per-wave per-iter issue: 5 A + 1 idx + 4 B + 4 B = 14.
//   A: fp32 rows direct to LDS, dbuf 2x40KB, 1-iteration latency cover.
//   B: two 32KB half-K subtiles, reloaded right after each half's MFMA.
//   idx: LDS ring depth 2, each wave loads its own 20 rows (width-4).
// ---------------------------------------------------------------------------
__global__ __launch_bounds__(512, 2) void fused_gemm1_k(
    const float* __restrict__ x_raw, const int* __restrict__ x_idx,
    const float* __restrict__ emb, const bf16* __restrict__ W1t,
    const float* __restrict__ b1, const float* __restrict__ S01,
    bf16* __restrict__ h1)
{
    extern __shared__ char smem[];
    char* Als  = smem;                  // 2 x [160 rows][256B fp32] = 81920
    char* Bls  = smem + 81920;          // 2 x [512 rows][64B bf16]  = 65536
    char* ring = smem + 81920 + 65536;  // 2 slots x 8 waves x 80B   = 1280

    const int tid = threadIdx.x;
    const int w  = tid >> 6, l = tid & 63;
    const int wr = w >> 2, wc = w & 3;          // 2 x 4 wave grid
    const int fr = l & 15, fq = l >> 4;
    const int m0 = blockIdx.x * 160;

    const int arow_sub = l >> 4;                // 0..3   (A: 4 rows/instr)
    const int acol     = l & 15;                // 16B unit within 256B row
    const int brow_sub = l >> 2;                // 0..15  (B: 16 rows/instr)
    const int bcol     = l & 3;                 // 16B unit within 64B row

    f32x4 acc[5][8] = {};

    auto issue_idx = [&](int t, int slot) {     // 1 instr/wave (lanes 0..19)
        if (l < 20)
            gload4((const char*)x_idx + ((size_t)(m0 + w * 20 + l) * T_ + t) * 4,
                   ring + slot * 640 + w * 80);
    };
    auto issue_A = [&](int t, int buf, const int (&iv)[5]) {   // 5 instr/wave
        char* dst = Als + buf * 40960 + (w * 20) * 256;
        #pragma unroll
        for (int p = 0; p < 5; ++p) {
            int row = w * 20 + p * 4 + arow_sub;
            const char* src = (const char*)(emb + ((size_t)t * V_ + (size_t)iv[p]) * D_)
                              + ((acol * 16) ^ ((row & 7) << 4));
            gload16(src, dst + p * 1024);
        }
    };
    auto issue_B = [&](int t, int h) {          // 4 instr/wave
        char* dst = Bls + h * 32768 + w * 4096;
        #pragma unroll
        for (int i = 0; i < 4; ++i) {
            int row = w * 64 + i * 16 + brow_sub;
            const char* src = (const char*)W1t + ((size_t)row * KE + t * 64 + h * 32) * 2
                              + ((bcol * 16) ^ ((row & 3) << 4));
            gload16(src, dst + i * 1024);
        }
    };
    auto read_iv = [&](int slot, int (&iv)[5]) {
        const int* ivp = (const int*)(ring + slot * 640 + w * 80);
        #pragma unroll
        for (int p = 0; p < 5; ++p) iv[p] = ivp[p * 4 + arow_sub];
    };
    auto mfma_half = [&](int abuf, int kk) {
        const char* Ab = Als + abuf * 40960;
        bf16x8 af[5];
        #pragma unroll
        for (int i = 0; i < 5; ++i) {
            int r  = wr * 80 + i * 16 + fr;
            int xr = (r & 7) << 4;
            float4 a0 = *(const float4*)(Ab + r * 256 + ((kk * 128 + fq * 32) ^ xr));
            float4 a1 = *(const float4*)(Ab + r * 256 + ((kk * 128 + fq * 32 + 16) ^ xr));
            bf16x8 t;
            t[0] = (__bf16)a0.x; t[1] = (__bf16)a0.y;
            t[2] = (__bf16)a0.z; t[3] = (__bf16)a0.w;
            t[4] = (__bf16)a1.x; t[5] = (__bf16)a1.y;
            t[6] = (__bf16)a1.z; t[7] = (__bf16)a1.w;
            af[i] = t;
        }
        const char* Bb = Bls + kk * 32768;
        #pragma unroll
        for (int j = 0; j < 8; ++j) {
            int n = wc * 128 + j * 16 + fr;
            bf16x8 bg = *(const bf16x8*)(Bb + n * 64 + ((fq * 16) ^ ((n & 3) << 4)));
            #pragma unroll
            for (int i = 0; i < 5; ++i)
                acc[i][j] = __builtin_amdgcn_mfma_f32_16x16x32_bf16(
                    af[i], bg, acc[i][j], 0, 0, 0);
        }
    };

    // ---- prologue -------------------------------------------------------
    int iv[5];
    issue_idx(0, 0);                              // idx(0) -> slot0
    asm volatile("s_waitcnt vmcnt(0)" ::: "memory");   // own-wave data only
    read_iv(0, iv);
    issue_A(0, 0, iv);                            // A(0) -> Abuf0   (+5)
    issue_idx(1, 1);                              // idx(1) -> slot1 (+1)
    issue_B(0, 0);                                // B(0,h0)         (+4)
    issue_B(0, 1);                                // B(0,h1)         (+4)
    // in-flight stack: [A 5, idx 1, Bh0 4, Bh1 4] = 14  (steady invariant)

    // ---- main loop ------------------------------------------------------
    for (int kt = 0; kt < NKT; ++kt) {
        int tA = (kt + 1 < NKT) ? kt + 1 : NKT - 1;   // clamp keeps counts uniform
        int t2 = (kt + 2 < NKT) ? kt + 2 : NKT - 1;

        asm volatile("s_waitcnt vmcnt(8)" ::: "memory");   // idx(kt+1), A(kt) done
        read_iv((kt + 1) & 1, iv);
        issue_A(tA, (kt + 1) & 1, iv);                     // +5
        issue_idx(t2, kt & 1);                             // +1
        asm volatile("s_waitcnt vmcnt(10)" ::: "memory");  // B(kt,h0) done
        __builtin_amdgcn_s_barrier();
        __builtin_amdgcn_sched_barrier(0);

        __builtin_amdgcn_s_setprio(1);
        mfma_half(kt & 1, 0);
        __builtin_amdgcn_s_setprio(0);
        asm volatile("s_waitcnt lgkmcnt(0)" ::: "memory"); // LDS reads retired
        __builtin_amdgcn_s_barrier();

        issue_B(tA, 0);                                    // +4 (overwrite Bsub0)
        asm volatile("s_waitcnt vmcnt(10)" ::: "memory");  // B(kt,h1) done
        __builtin_amdgcn_s_barrier();
        __builtin_amdgcn_sched_barrier(0);

        __builtin_amdgcn_s_setprio(1);
        mfma_half(kt & 1, 1);
        __builtin_amdgcn_s_setprio(0);
        asm volatile("s_waitcnt lgkmcnt(0)" ::: "memory");
        __builtin_amdgcn_s_barrier();

        issue_B(tA, 1);                                    // +4 (overwrite Bsub1)
        // stack back to [A 5, idx 1, Bh0 4, Bh1 4] = 14
    }
    asm volatile("s_waitcnt vmcnt(0)" ::: "memory");       // drain clamped junk

    // ---- epilogue: bias + rank-2 raw contribution + relu -> h1 ---------
    const float* S0 = S01;
    const float* S1 = S01 + H1_;
    #pragma unroll
    for (int i = 0; i < 5; ++i) {
        int rbase = wr * 80 + i * 16 + fq * 4;
        float x0[4], x1[4];
        #pragma unroll
        for (int r2 = 0; r2 < 4; ++r2) {
            int m = m0 + rbase + r2;
            x0[r2] = x_raw[2 * m];
            x1[r2] = x_raw[2 * m + 1];
        }
        #pragma unroll
        for (int j = 0; j < 8; ++j) {
            int n = wc * 128 + j * 16 + fr;
            float bb = b1[n], s0 = S0[n], s1 = S1[n];
            #pragma unroll
            for (int r2 = 0; r2 < 4; ++r2) {
                float v = acc[i][j][r2] + bb + x0[r2] * s0 + x1[r2] * s1;
                h1[(size_t)(m0 + rbase + r2) * H1_ + n] =
                    __float2bfloat16(fmaxf(v, 0.0f));
            }
        }
    }
}

// ---------------------------------------------------------------------------
// FUSED GEMM2 + head (R3/R4-proven, ~8us):  h2 = relu(h1 @ W2 + b2);
// logits = h2 @ W3 + b3; softmax over P=20.  BM=160 (=8 batches), BN=256.
// ---------------------------------------------------------------------------
__global__ __launch_bounds__(512) void gemm2_head_k(
    const bf16* __restrict__ h1, const bf16* __restrict__ W2t,
    const float* __restrict__ b2, const float* __restrict__ W3,
    const float* __restrict__ b3, float* __restrict__ out)
{
    __shared__ char  As[20480];       // [160][64] bf16 swizzled
    __shared__ char  Bs[32768];       // [256][64] bf16 swizzled
    __shared__ float w3s[H2_];
    __shared__ float b2s[H2_];
    __shared__ float logq[4][160];
    __shared__ float logits[160];

    const int tid = threadIdx.x;
    const int w = tid >> 6, l = tid & 63;
    const int wr = w >> 2, wc = w & 3;
    const int fr = l & 15, fq = l >> 4;
    const int m0 = blockIdx.x * 160;
    const int r8 = l >> 3, c8 = l & 7;

    if (tid < H2_) { w3s[tid] = W3[tid]; b2s[tid] = b2[tid]; }

    f32x4 acc[5][4] = {};

    for (int kt = 0; kt < 8; ++kt) {
        for (int s = w; s < 20; s += 8) {
            int row = s * 8 + r8;
            const char* src = (const char*)(h1 + (size_t)(m0 + row) * H1_ + kt * 64)
                              + ((16 * c8) ^ ((row & 7) << 4));
            gload16(src, As + s * 1024);
        }
        #pragma unroll
        for (int q = 0; q < 4; ++q) {
            int s = q * 8 + w;
            int row = s * 8 + r8;
            const char* src = (const char*)(W2t + (size_t)row * H1_ + kt * 64)
                              + ((16 * c8) ^ ((row & 7) << 4));
            gload16(src, Bs + s * 1024);
        }
        __syncthreads();

        #pragma unroll
        for (int kk = 0; kk < 2; ++kk) {
            bf16x8 af[5];
            #pragma unroll
            for (int i = 0; i < 5; ++i) {
                int r = wr * 80 + i * 16 + fr;
                int byte = (r * 128 + kk * 64 + fq * 16) ^ ((r & 7) << 4);
                af[i] = *(const bf16x8*)(As + byte);
            }
            #pragma unroll
            for (int j = 0; j < 4; ++j) {
                int n = wc * 64 + j * 16 + fr;
                int byte = (n * 128 + kk * 64 + fq * 16) ^ ((n & 7) << 4);
                bf16x8 bg = *(const bf16x8*)(Bs + byte);
                #pragma unroll
                for (int i = 0; i < 5; ++i)
                    acc[i][j] = __builtin_amdgcn_mfma_f32_16x16x32_bf16(
                        af[i], bg, acc[i][j], 0, 0, 0);
            }
        }
        __syncthreads();
    }

    #pragma unroll
    for (int i = 0; i < 5; ++i) {
        #pragma unroll
        for (int r2 = 0; r2 < 4; ++r2) {
            float s = 0.f;
            #pragma unroll
            for (int j = 0; j < 4; ++j) {
                int col = wc * 64 + j * 16 + fr;
                float v = fmaxf(acc[i][j][r2] + b2s[col], 0.f);
                s += v * w3s[col];
            }
            #pragma unroll
            for (int off = 1; off < 16; off <<= 1) s += __shfl_xor(s, off);
            if (fr == 0)
                logq[wc][wr * 80 + i * 16 + fq * 4 + r2] = s;
        }
    }
    __syncthreads();
    if (tid < 160)
        logits[tid] = logq[0][tid] + logq[1][tid] + logq[2][tid] + logq[3][tid] + b3[0];
    __syncthreads();
    if (tid < 160) {
        int bb = (tid / 20) * 20;
        float mx = -1e30f;
        #pragma unroll
        for (int p = 0; p < 20; ++p) mx = fmaxf(mx, logits[bb + p]);
        float sum = 0.f;
        #pragma unroll
        for (int p = 0; p < 20; ++p) sum += expf(logits[bb + p] - mx);
        out[m0 + tid] = expf(logits[tid] - mx) / sum;
    }
}

// ---------------------------------------------------------------------------
extern "C" void kernel_launch(void* const* d_in, const int* in_sizes, int n_in,
                              void* d_out, int out_size, void* d_ws, size_t ws_size,
                              hipStream_t stream)
{
    const float* x_raw = (const float*)d_in[0];
    const int*   x_idx = (const int*)  d_in[1];
    const float* emb   = (const float*)d_in[2];
    const float* W1    = (const float*)d_in[3];
    const float* b1    = (const float*)d_in[4];
    const float* W2    = (const float*)d_in[5];
    const float* b2    = (const float*)d_in[6];
    const float* W3    = (const float*)d_in[7];
    const float* b3    = (const float*)d_in[8];

    char* ws = (char*)d_ws;
    size_t off = 0;
    bf16*  W1t = (bf16*) (ws + off); off += (size_t)H1_ * KE * 2;    // 2.16 MB
    bf16*  W2t = (bf16*) (ws + off); off += (size_t)H2_ * H1_ * 2;   // 0.26 MB
    float* S01 = (float*)(ws + off); off += (size_t)2 * H1_ * 4;     // 4 KB
    bf16*  h1  = (bf16*) (ws + off); off += (size_t)M_ * H1_ * 2;    // 42 MB

    // prep
    colsum_k<<<4, 256, 0, stream>>>(W1, S01);
    w1t_k<<<(H1_ * KE) / 256, 256, 0, stream>>>(W1, W1t);
    transpose_bf16_k<<<(H2_ * H1_ + 255) / 256, 256, 0, stream>>>(W2, W2t, H1_, H2_);

    // fused gather + GEMM1 (145.25 KB dynamic LDS)
    hipFuncSetAttribute((const void*)fused_gemm1_k,
                        hipFuncAttributeMaxDynamicSharedMemorySize, 148736);
    fused_gemm1_k<<<256, 512, 148736, stream>>>(x_raw, x_idx, emb, W1t, b1, S01, h1);

    // fused GEMM2 + head -> softmax out
    gemm2_head_k<<<256, 512, 0, stream>>>(h1, W2t, b2, W3, b3, (float*)d_out);
}